// Round 1
// baseline (2950.152 us; speedup 1.0000x reference)
//
#include <hip/hip_runtime.h>
#include <hip/hip_bf16.h>

// LLaMA layer, MI355X baseline.
// Structure: rmsnorm -> Q GEMM (wk/wv are dead code: reference attention only
// uses past_k/past_v) -> fused rope+attention -> cast -> O GEMM -> rmsnorm ->
// w1/w3 GEMMs -> silu-mul -> w2 GEMM.
// All GEMMs: C[M,N] = A[M,K] @ W[N,K]^T, A bf16 (in ws), W fp32 (converted
// to bf16 during LDS staging), C fp32. 16x16x32 bf16 MFMA, 128x128 tiles,
// 4x4 16x16 tiles per wave, LDS rows padded 32->40 (2-way bank alias = free).

typedef __attribute__((ext_vector_type(4))) float  floatx4;
typedef __attribute__((ext_vector_type(8))) __bf16 bf16x8;
typedef __attribute__((ext_vector_type(4))) __bf16 bf16x4;

#define HIDDEN 4096
#define FFN    11008
#define SEQLEN 1024
#define NHEADS 32
#define HDIM   128
#define PAST   1024

// ---------------- rmsnorm (fp32 in -> bf16 out), one block per row ----------
__global__ __launch_bounds__(256) void rmsnorm_bf16(
    const float* __restrict__ x, const float* __restrict__ w,
    __bf16* __restrict__ out)
{
    const int row = blockIdx.x;
    const float* xr = x + (size_t)row * HIDDEN;
    float4 v[4];
    float ss = 0.f;
#pragma unroll
    for (int i = 0; i < 4; ++i) {
        v[i] = *(const float4*)(xr + threadIdx.x * 4 + i * 1024);
        ss += v[i].x * v[i].x + v[i].y * v[i].y + v[i].z * v[i].z + v[i].w * v[i].w;
    }
#pragma unroll
    for (int off = 32; off > 0; off >>= 1) ss += __shfl_down(ss, off);
    __shared__ float red[4];
    if ((threadIdx.x & 63) == 0) red[threadIdx.x >> 6] = ss;
    __syncthreads();
    float total = red[0] + red[1] + red[2] + red[3];
    float scale = rsqrtf(total * (1.f / HIDDEN) + 1e-6f);
#pragma unroll
    for (int i = 0; i < 4; ++i) {
        int idx = threadIdx.x * 4 + i * 1024;
        float4 wv = *(const float4*)(w + idx);
        bf16x4 o;
        o[0] = (__bf16)(v[i].x * scale * wv.x);
        o[1] = (__bf16)(v[i].y * scale * wv.y);
        o[2] = (__bf16)(v[i].z * scale * wv.z);
        o[3] = (__bf16)(v[i].w * scale * wv.w);
        *(bf16x4*)(out + (size_t)row * HIDDEN + idx) = o;
    }
}

// ---------------- GEMM: C[M,N] = A[M,K](bf16) @ W[N,K]^T(fp32) ---------------
__global__ __launch_bounds__(256) void gemm_bt(
    const __bf16* __restrict__ A, const float* __restrict__ W,
    float* __restrict__ C, int M, int N, int K)
{
    __shared__ __bf16 As[128][40];   // 32 k + pad to 40
    __shared__ __bf16 Bs[128][40];

    const int tid  = threadIdx.x;
    const int bn   = blockIdx.x;   // N/128
    const int bm   = blockIdx.y;   // M/128
    const int wave = tid >> 6;
    const int lane = tid & 63;
    const int wr   = wave >> 1;    // 0..1 : 64-row half
    const int wc   = wave & 1;     // 0..1 : 64-col half
    const int lrow = lane & 15;
    const int quad = lane >> 4;    // 0..3

    floatx4 acc[4][4] = {};

    for (int k0 = 0; k0 < K; k0 += 32) {
        // stage A: 128 rows x 32 k bf16, 512 chunks of 8
#pragma unroll
        for (int i = 0; i < 2; ++i) {
            int id = tid + i * 256;
            int r = id >> 2, cc = id & 3;
            bf16x8 av = *(const bf16x8*)(A + (size_t)(bm * 128 + r) * K + k0 + cc * 8);
            *(bf16x8*)(&As[r][cc * 8]) = av;
        }
        // stage W: 128 rows x 32 k fp32 -> bf16, 1024 chunks of 4
#pragma unroll
        for (int i = 0; i < 4; ++i) {
            int id = tid + i * 256;
            int r = id >> 3, cc = id & 7;
            float4 wv = *(const float4*)(W + (size_t)(bn * 128 + r) * K + k0 + cc * 4);
            bf16x4 bv;
            bv[0] = (__bf16)wv.x; bv[1] = (__bf16)wv.y;
            bv[2] = (__bf16)wv.z; bv[3] = (__bf16)wv.w;
            *(bf16x4*)(&Bs[r][cc * 4]) = bv;
        }
        __syncthreads();

        bf16x8 af[4], bfr[4];
#pragma unroll
        for (int i = 0; i < 4; ++i)
            af[i] = *(const bf16x8*)(&As[wr * 64 + i * 16 + lrow][quad * 8]);
#pragma unroll
        for (int j = 0; j < 4; ++j)
            bfr[j] = *(const bf16x8*)(&Bs[wc * 64 + j * 16 + lrow][quad * 8]);
#pragma unroll
        for (int i = 0; i < 4; ++i)
#pragma unroll
            for (int j = 0; j < 4; ++j)
                acc[i][j] = __builtin_amdgcn_mfma_f32_16x16x32_bf16(af[i], bfr[j], acc[i][j], 0, 0, 0);
        __syncthreads();
    }

    // epilogue: D row = quad*4+reg, col = lane&15
#pragma unroll
    for (int i = 0; i < 4; ++i) {
        int mrow = bm * 128 + wr * 64 + i * 16 + quad * 4;
#pragma unroll
        for (int j = 0; j < 4; ++j) {
            int ncol = bn * 128 + wc * 64 + j * 16 + lrow;
            float* cp = C + (size_t)mrow * N + ncol;
#pragma unroll
            for (int r = 0; r < 4; ++r)
                cp[(size_t)r * N] = acc[i][j][r];
        }
    }
}

// ---------------- fused rope + attention --------------------------------
// block = (q-tile of 8 rows, head). xq layout [s][h*128+d] (pre-rope).
// past_k/past_v: [h][p][d]. out: [s][h*128+d].
#define TQ 8
__global__ __launch_bounds__(256) void attn_kernel(
    const float* __restrict__ xq, const float* __restrict__ pk,
    const float* __restrict__ pv, float* __restrict__ out)
{
    const int qt = blockIdx.x;   // 0..127
    const int h  = blockIdx.y;   // 0..31
    const int s0 = qt * TQ;
    const int tid = threadIdx.x;

    __shared__ float qs[TQ][128];
    __shared__ float kv[32][129];     // pad 129: (pl+d)%32 -> conflict-free
    __shared__ float sc[TQ][1024];

    // phase 0: load q rows + apply rope
    for (int idx = tid; idx < TQ * 128; idx += 256) {
        int qi = idx >> 7, j2 = idx & 127;
        int j = j2 & 63;
        int s = s0 + qi;
        const float* qrow = xq + (size_t)s * HIDDEN + h * HDIM;
        float xe = qrow[2 * j];
        float xo = qrow[2 * j + 1];
        float freq = __powf(10000.f, -(float)(2 * j) * (1.f / 128.f));
        float ang = (float)s * freq;
        float sn, cs;
        __sincosf(ang, &sn, &cs);
        qs[qi][j2] = (j2 < 64) ? (xe * cs - xo * sn) : (xe * sn + xo * cs);
    }
    __syncthreads();

    // phase 1: scores = q . k  (p-tiles of 32)
    const int qi1 = tid >> 5, pl1 = tid & 31;
    for (int pt = 0; pt < 32; ++pt) {
        const float* kbase = pk + ((size_t)h * PAST + pt * 32) * HDIM;
#pragma unroll
        for (int i = 0; i < 4; ++i) {
            int id = tid + i * 256;
            int p = id >> 5, cc = id & 31;
            float4 v = *(const float4*)(kbase + p * HDIM + cc * 4);
            kv[p][cc * 4 + 0] = v.x; kv[p][cc * 4 + 1] = v.y;
            kv[p][cc * 4 + 2] = v.z; kv[p][cc * 4 + 3] = v.w;
        }
        __syncthreads();
        float acc = 0.f;
        for (int d = 0; d < 128; ++d)
            acc += qs[qi1][d] * kv[pl1][d];
        sc[qi1][pt * 32 + pl1] = acc;
        __syncthreads();
    }

    // phase 2: softmax per q row, 32 lanes per row (shfl stays in 32-group)
    {
        int qi = tid >> 5, l = tid & 31;
        float mx = -1e30f;
        for (int p = l; p < 1024; p += 32) mx = fmaxf(mx, sc[qi][p]);
#pragma unroll
        for (int off = 16; off > 0; off >>= 1) mx = fmaxf(mx, __shfl_xor(mx, off));
        float sum = 0.f;
        for (int p = l; p < 1024; p += 32) {
            float e = __expf(sc[qi][p] - mx);
            sc[qi][p] = e; sum += e;
        }
#pragma unroll
        for (int off = 16; off > 0; off >>= 1) sum += __shfl_xor(sum, off);
        float inv = 1.f / sum;
        for (int p = l; p < 1024; p += 32) sc[qi][p] *= inv;
    }
    __syncthreads();

    // phase 3: out[qi][d] = sum_p w * v
    float acc3[4] = {0.f, 0.f, 0.f, 0.f};
    const int d = tid & 127, qg = tid >> 7;   // qg 0..1, qi = qg + 2*i
    for (int pt = 0; pt < 32; ++pt) {
        const float* vbase = pv + ((size_t)h * PAST + pt * 32) * HDIM;
#pragma unroll
        for (int i = 0; i < 4; ++i) {
            int id = tid + i * 256;
            int p = id >> 5, cc = id & 31;
            float4 v = *(const float4*)(vbase + p * HDIM + cc * 4);
            kv[p][cc * 4 + 0] = v.x; kv[p][cc * 4 + 1] = v.y;
            kv[p][cc * 4 + 2] = v.z; kv[p][cc * 4 + 3] = v.w;
        }
        __syncthreads();
        for (int pl = 0; pl < 32; ++pl) {
            float vv = kv[pl][d];
#pragma unroll
            for (int i = 0; i < 4; ++i)
                acc3[i] += sc[qg + 2 * i][pt * 32 + pl] * vv;
        }
        __syncthreads();
    }
#pragma unroll
    for (int i = 0; i < 4; ++i) {
        int qi = qg + 2 * i;
        out[(size_t)(s0 + qi) * HIDDEN + h * HDIM + d] = acc3[i];
    }
}

// ---------------- elementwise ------------------------------------------
__global__ __launch_bounds__(256) void cast_bf16_kernel(
    const float* __restrict__ in, __bf16* __restrict__ out)
{
    int i = (blockIdx.x * 256 + threadIdx.x) * 4;
    float4 v = *(const float4*)(in + i);
    bf16x4 o;
    o[0] = (__bf16)v.x; o[1] = (__bf16)v.y; o[2] = (__bf16)v.z; o[3] = (__bf16)v.w;
    *(bf16x4*)(out + i) = o;
}

__global__ __launch_bounds__(256) void silu_mul_bf16(
    const float* __restrict__ x1, const float* __restrict__ x3,
    __bf16* __restrict__ out)
{
    int i = (blockIdx.x * 256 + threadIdx.x) * 4;
    float4 a = *(const float4*)(x1 + i);
    float4 b = *(const float4*)(x3 + i);
    bf16x4 o;
    o[0] = (__bf16)(a.x * (b.x / (1.f + __expf(-b.x))));
    o[1] = (__bf16)(a.y * (b.y / (1.f + __expf(-b.y))));
    o[2] = (__bf16)(a.z * (b.z / (1.f + __expf(-b.z))));
    o[3] = (__bf16)(a.w * (b.w / (1.f + __expf(-b.w))));
    *(bf16x4*)(out + i) = o;
}

// ---------------- launch -------------------------------------------------
extern "C" void kernel_launch(void* const* d_in, const int* in_sizes, int n_in,
                              void* d_out, int out_size, void* d_ws, size_t ws_size,
                              hipStream_t stream)
{
    const float* x   = (const float*)d_in[0];
    const float* wq  = (const float*)d_in[1];
    // d_in[2]=wk, d_in[3]=wv: structurally dead (attention uses only past_k/v)
    const float* wo  = (const float*)d_in[4];
    const float* w1  = (const float*)d_in[5];
    const float* w2  = (const float*)d_in[6];
    const float* w3  = (const float*)d_in[7];
    const float* anw = (const float*)d_in[8];
    const float* fnw = (const float*)d_in[9];
    const float* pk  = (const float*)d_in[10];
    const float* pv  = (const float*)d_in[11];
    float* out = (float*)d_out;

    char* ws = (char*)d_ws;
    constexpr size_t MB = 1ull << 20;
    __bf16* h_bf  = (__bf16*)(ws);              // 8 MB
    float*  xq    = (float*)(ws + 8 * MB);      // 16 MB
    float*  ao    = (float*)(ws + 24 * MB);     // 16 MB
    __bf16* ao_bf = (__bf16*)(ws + 40 * MB);    // 8 MB
    float*  xo    = (float*)(ws + 48 * MB);     // 16 MB
    __bf16* hf_bf = (__bf16*)(ws + 64 * MB);    // 8 MB
    float*  x1    = (float*)(ws + 72 * MB);     // 43 MB
    float*  x3    = (float*)(ws + 116 * MB);    // 43 MB
    __bf16* g_bf  = (__bf16*)(ws + 160 * MB);   // 21.5 MB -> total ~182 MB

    rmsnorm_bf16<<<SEQLEN, 256, 0, stream>>>(x, anw, h_bf);
    gemm_bt<<<dim3(HIDDEN / 128, SEQLEN / 128), 256, 0, stream>>>(h_bf, wq, xq, SEQLEN, HIDDEN, HIDDEN);
    attn_kernel<<<dim3(SEQLEN / TQ, NHEADS), 256, 0, stream>>>(xq, pk, pv, ao);
    cast_bf16_kernel<<<(SEQLEN * HIDDEN) / 1024, 256, 0, stream>>>(ao, ao_bf);
    gemm_bt<<<dim3(HIDDEN / 128, SEQLEN / 128), 256, 0, stream>>>(ao_bf, wo, xo, SEQLEN, HIDDEN, HIDDEN);
    rmsnorm_bf16<<<SEQLEN, 256, 0, stream>>>(xo, fnw, hf_bf);
    gemm_bt<<<dim3(FFN / 128, SEQLEN / 128), 256, 0, stream>>>(hf_bf, w1, x1, SEQLEN, FFN, HIDDEN);
    gemm_bt<<<dim3(FFN / 128, SEQLEN / 128), 256, 0, stream>>>(hf_bf, w3, x3, SEQLEN, FFN, HIDDEN);
    silu_mul_bf16<<<(SEQLEN * FFN) / 1024, 256, 0, stream>>>(x1, x3, g_bf);
    gemm_bt<<<dim3(HIDDEN / 128, SEQLEN / 128), 256, 0, stream>>>(g_bf, w2, out, SEQLEN, HIDDEN, FFN);
}

// Round 2
// 1679.540 us; speedup vs baseline: 1.7565x; 1.7565x over previous
//
#include <hip/hip_runtime.h>
#include <hip/hip_bf16.h>

// LLaMA layer, MI355X. Round 2: MFMA flash attention.
// rmsnorm -> Q GEMM (wk/wv dead: reference attention uses only past_k/v)
// -> rope_cast (bf16 roped Q) -> attn_flash (MFMA, online softmax, bf16 out)
// -> O GEMM -> rmsnorm -> w1/w3 GEMMs -> silu-mul -> w2 GEMM.
// GEMMs: C[M,N] = A[M,K](bf16) @ W[N,K]^T(fp32->bf16 in staging), 16x16x32 MFMA.

typedef __attribute__((ext_vector_type(4))) float  floatx4;
typedef __attribute__((ext_vector_type(8))) __bf16 bf16x8;
typedef __attribute__((ext_vector_type(4))) __bf16 bf16x4;

#define HIDDEN 4096
#define FFN    11008
#define SEQLEN 1024
#define NHEADS 32
#define HDIM   128
#define PAST   1024

// ---------------- rmsnorm (fp32 in -> bf16 out), one block per row ----------
__global__ __launch_bounds__(256) void rmsnorm_bf16(
    const float* __restrict__ x, const float* __restrict__ w,
    __bf16* __restrict__ out)
{
    const int row = blockIdx.x;
    const float* xr = x + (size_t)row * HIDDEN;
    float4 v[4];
    float ss = 0.f;
#pragma unroll
    for (int i = 0; i < 4; ++i) {
        v[i] = *(const float4*)(xr + threadIdx.x * 4 + i * 1024);
        ss += v[i].x * v[i].x + v[i].y * v[i].y + v[i].z * v[i].z + v[i].w * v[i].w;
    }
#pragma unroll
    for (int off = 32; off > 0; off >>= 1) ss += __shfl_down(ss, off);
    __shared__ float red[4];
    if ((threadIdx.x & 63) == 0) red[threadIdx.x >> 6] = ss;
    __syncthreads();
    float total = red[0] + red[1] + red[2] + red[3];
    float scale = rsqrtf(total * (1.f / HIDDEN) + 1e-6f);
#pragma unroll
    for (int i = 0; i < 4; ++i) {
        int idx = threadIdx.x * 4 + i * 1024;
        float4 wv = *(const float4*)(w + idx);
        bf16x4 o;
        o[0] = (__bf16)(v[i].x * scale * wv.x);
        o[1] = (__bf16)(v[i].y * scale * wv.y);
        o[2] = (__bf16)(v[i].z * scale * wv.z);
        o[3] = (__bf16)(v[i].w * scale * wv.w);
        *(bf16x4*)(out + (size_t)row * HIDDEN + idx) = o;
    }
}

// ---------------- GEMM: C[M,N] = A[M,K](bf16) @ W[N,K]^T(fp32) ---------------
__global__ __launch_bounds__(256) void gemm_bt(
    const __bf16* __restrict__ A, const float* __restrict__ W,
    float* __restrict__ C, int M, int N, int K)
{
    __shared__ __bf16 As[128][40];   // 32 k + pad to 40
    __shared__ __bf16 Bs[128][40];

    const int tid  = threadIdx.x;
    const int bn   = blockIdx.x;   // N/128
    const int bm   = blockIdx.y;   // M/128
    const int wave = tid >> 6;
    const int lane = tid & 63;
    const int wr   = wave >> 1;    // 0..1 : 64-row half
    const int wc   = wave & 1;     // 0..1 : 64-col half
    const int lrow = lane & 15;
    const int quad = lane >> 4;    // 0..3

    floatx4 acc[4][4] = {};

    for (int k0 = 0; k0 < K; k0 += 32) {
        // stage A: 128 rows x 32 k bf16, 512 chunks of 8
#pragma unroll
        for (int i = 0; i < 2; ++i) {
            int id = tid + i * 256;
            int r = id >> 2, cc = id & 3;
            bf16x8 av = *(const bf16x8*)(A + (size_t)(bm * 128 + r) * K + k0 + cc * 8);
            *(bf16x8*)(&As[r][cc * 8]) = av;
        }
        // stage W: 128 rows x 32 k fp32 -> bf16, 1024 chunks of 4
#pragma unroll
        for (int i = 0; i < 4; ++i) {
            int id = tid + i * 256;
            int r = id >> 3, cc = id & 7;
            float4 wv = *(const float4*)(W + (size_t)(bn * 128 + r) * K + k0 + cc * 4);
            bf16x4 bv;
            bv[0] = (__bf16)wv.x; bv[1] = (__bf16)wv.y;
            bv[2] = (__bf16)wv.z; bv[3] = (__bf16)wv.w;
            *(bf16x4*)(&Bs[r][cc * 4]) = bv;
        }
        __syncthreads();

        bf16x8 af[4], bfr[4];
#pragma unroll
        for (int i = 0; i < 4; ++i)
            af[i] = *(const bf16x8*)(&As[wr * 64 + i * 16 + lrow][quad * 8]);
#pragma unroll
        for (int j = 0; j < 4; ++j)
            bfr[j] = *(const bf16x8*)(&Bs[wc * 64 + j * 16 + lrow][quad * 8]);
#pragma unroll
        for (int i = 0; i < 4; ++i)
#pragma unroll
            for (int j = 0; j < 4; ++j)
                acc[i][j] = __builtin_amdgcn_mfma_f32_16x16x32_bf16(af[i], bfr[j], acc[i][j], 0, 0, 0);
        __syncthreads();
    }

    // epilogue: D row = quad*4+reg, col = lane&15
#pragma unroll
    for (int i = 0; i < 4; ++i) {
        int mrow = bm * 128 + wr * 64 + i * 16 + quad * 4;
#pragma unroll
        for (int j = 0; j < 4; ++j) {
            int ncol = bn * 128 + wc * 64 + j * 16 + lrow;
            float* cp = C + (size_t)mrow * N + ncol;
#pragma unroll
            for (int r = 0; r < 4; ++r)
                cp[(size_t)r * N] = acc[i][j][r];
        }
    }
}

// ---------------- rope + cast to bf16: one block per sequence position ------
__global__ __launch_bounds__(256) void rope_cast(
    const float* __restrict__ xq, __bf16* __restrict__ outq)
{
    const int s = blockIdx.x;
    const float* row = xq + (size_t)s * HIDDEN;
    __bf16* orow = outq + (size_t)s * HIDDEN;
    for (int idx = threadIdx.x; idx < HIDDEN; idx += 256) {
        int d = idx & 127;         // dim within head
        int j = d & 63;            // rope pair index
        int base = idx - d;        // h*128
        float xe = row[base + 2 * j];
        float xo = row[base + 2 * j + 1];
        float freq = __powf(10000.f, -(float)(2 * j) * (1.f / 128.f));
        float sn, cs;
        __sincosf((float)s * freq, &sn, &cs);
        float v = (d < 64) ? (xe * cs - xo * sn) : (xe * sn + xo * cs);
        orow[idx] = (__bf16)v;
    }
}

// ---------------- flash attention (MFMA) ------------------------------------
// block = (64-query tile, head). q: roped bf16 [s][4096]. pk/pv: [h][1024][128].
// out: bf16 [s][4096]. Per wave: 16 q rows; online softmax; no scale factor
// (reference einsum has none). P routes C-layout -> LDS -> A-layout.
__global__ __launch_bounds__(256) void attn_flash(
    const __bf16* __restrict__ q, const float* __restrict__ pk,
    const float* __restrict__ pv, __bf16* __restrict__ out)
{
    const int qt = blockIdx.x;     // 0..15
    const int h  = blockIdx.y;     // 0..31
    const int s0 = qt * 64;
    const int tid  = threadIdx.x;
    const int wave = tid >> 6;
    const int lane = tid & 63;
    const int l15  = lane & 15;
    const int quad = lane >> 4;

    __shared__ __bf16 Ks[64 * 136];   // [p][d], row stride 136 (272B, 16B-aligned)
    __shared__ __bf16 Vt[128 * 72];   // [d][p], row stride 72 (144B, 16B-aligned)
    __shared__ __bf16 Ps[64 * 72];    // [q][p], row stride 72

    // Q fragments: rows wave*16 + l15, 4 k-steps of 32 dims
    bf16x8 qf[4];
    {
        const __bf16* qrow = q + (size_t)(s0 + wave * 16 + l15) * HIDDEN + h * HDIM;
#pragma unroll
        for (int ks = 0; ks < 4; ++ks)
            qf[ks] = *(const bf16x8*)(qrow + ks * 32 + quad * 8);
    }

    floatx4 Oa[8] = {};
    float m_r[4], l_r[4];
#pragma unroll
    for (int r = 0; r < 4; ++r) { m_r[r] = -1e30f; l_r[r] = 0.f; }

    for (int p0 = 0; p0 < PAST; p0 += 64) {
        const float* kbase = pk + ((size_t)h * PAST + p0) * HDIM;
        const float* vbase = pv + ((size_t)h * PAST + p0) * HDIM;
        // stage K (row-major bf16) and V (transposed bf16): 2048 float4 chunks
#pragma unroll
        for (int i = 0; i < 8; ++i) {
            int f = i * 256 + tid;
            int p = f >> 5, dq = (f & 31) * 4;
            float4 k4 = *(const float4*)(kbase + p * HDIM + dq);
            bf16x4 kb;
            kb[0] = (__bf16)k4.x; kb[1] = (__bf16)k4.y;
            kb[2] = (__bf16)k4.z; kb[3] = (__bf16)k4.w;
            *(bf16x4*)(&Ks[p * 136 + dq]) = kb;
            float4 v4 = *(const float4*)(vbase + p * HDIM + dq);
            Vt[(dq + 0) * 72 + p] = (__bf16)v4.x;
            Vt[(dq + 1) * 72 + p] = (__bf16)v4.y;
            Vt[(dq + 2) * 72 + p] = (__bf16)v4.z;
            Vt[(dq + 3) * 72 + p] = (__bf16)v4.w;
        }
        __syncthreads();

        // S = Q K^T : per wave 16 q x 64 p
        floatx4 Sa[4] = {};
#pragma unroll
        for (int nb = 0; nb < 4; ++nb)
#pragma unroll
            for (int ks = 0; ks < 4; ++ks) {
                bf16x8 kf = *(const bf16x8*)(&Ks[(nb * 16 + l15) * 136 + ks * 32 + quad * 8]);
                Sa[nb] = __builtin_amdgcn_mfma_f32_16x16x32_bf16(qf[ks], kf, Sa[nb], 0, 0, 0);
            }

        // online softmax: lane owns rows quad*4 + r; 16-lane group shares rows
        float mnew[4];
#pragma unroll
        for (int r = 0; r < 4; ++r) {
            float t = fmaxf(fmaxf(Sa[0][r], Sa[1][r]), fmaxf(Sa[2][r], Sa[3][r]));
#pragma unroll
            for (int off = 1; off < 16; off <<= 1) t = fmaxf(t, __shfl_xor(t, off));
            mnew[r] = fmaxf(m_r[r], t);
        }
#pragma unroll
        for (int r = 0; r < 4; ++r) {
            float alpha = __expf(m_r[r] - mnew[r]);
            m_r[r] = mnew[r];
            float s = 0.f;
#pragma unroll
            for (int nb = 0; nb < 4; ++nb) {
                float e = __expf(Sa[nb][r] - mnew[r]);
                Sa[nb][r] = e;
                s += e;
            }
#pragma unroll
            for (int off = 1; off < 16; off <<= 1) s += __shfl_xor(s, off);
            l_r[r] = l_r[r] * alpha + s;
#pragma unroll
            for (int nb = 0; nb < 8; ++nb) Oa[nb][r] *= alpha;
        }

        // P -> LDS (C-layout scatter, bf16)
#pragma unroll
        for (int nb = 0; nb < 4; ++nb)
#pragma unroll
            for (int r = 0; r < 4; ++r)
                Ps[(wave * 16 + quad * 4 + r) * 72 + nb * 16 + l15] = (__bf16)Sa[nb][r];
        // each wave reads back only its own 16 rows -> no barrier needed;
        // compiler orders same-wave ds write->read via lgkmcnt.

        // O += P V : A = P (16q x 64p), B = V (64p x 128d)
#pragma unroll
        for (int ks2 = 0; ks2 < 2; ++ks2) {
            bf16x8 pf = *(const bf16x8*)(&Ps[(wave * 16 + l15) * 72 + ks2 * 32 + quad * 8]);
#pragma unroll
            for (int nb = 0; nb < 8; ++nb) {
                bf16x8 vf = *(const bf16x8*)(&Vt[(nb * 16 + l15) * 72 + ks2 * 32 + quad * 8]);
                Oa[nb] = __builtin_amdgcn_mfma_f32_16x16x32_bf16(pf, vf, Oa[nb], 0, 0, 0);
            }
        }
        __syncthreads();   // protect Ks/Vt before next stage
    }

    // epilogue: out rows s0 + wave*16 + quad*4 + r, cols h*128 + nb*16 + l15
    float inv[4];
#pragma unroll
    for (int r = 0; r < 4; ++r) inv[r] = 1.f / l_r[r];
#pragma unroll
    for (int nb = 0; nb < 8; ++nb)
#pragma unroll
        for (int r = 0; r < 4; ++r)
            out[(size_t)(s0 + wave * 16 + quad * 4 + r) * HIDDEN + h * HDIM + nb * 16 + l15] =
                (__bf16)(Oa[nb][r] * inv[r]);
}

// ---------------- elementwise ------------------------------------------
__global__ __launch_bounds__(256) void silu_mul_bf16(
    const float* __restrict__ x1, const float* __restrict__ x3,
    __bf16* __restrict__ out)
{
    int i = (blockIdx.x * 256 + threadIdx.x) * 4;
    float4 a = *(const float4*)(x1 + i);
    float4 b = *(const float4*)(x3 + i);
    bf16x4 o;
    o[0] = (__bf16)(a.x * (b.x / (1.f + __expf(-b.x))));
    o[1] = (__bf16)(a.y * (b.y / (1.f + __expf(-b.y))));
    o[2] = (__bf16)(a.z * (b.z / (1.f + __expf(-b.z))));
    o[3] = (__bf16)(a.w * (b.w / (1.f + __expf(-b.w))));
    *(bf16x4*)(out + i) = o;
}

// ---------------- launch -------------------------------------------------
extern "C" void kernel_launch(void* const* d_in, const int* in_sizes, int n_in,
                              void* d_out, int out_size, void* d_ws, size_t ws_size,
                              hipStream_t stream)
{
    const float* x   = (const float*)d_in[0];
    const float* wq  = (const float*)d_in[1];
    // d_in[2]=wk, d_in[3]=wv: structurally dead (attention uses only past_k/v)
    const float* wo  = (const float*)d_in[4];
    const float* w1  = (const float*)d_in[5];
    const float* w2  = (const float*)d_in[6];
    const float* w3  = (const float*)d_in[7];
    const float* anw = (const float*)d_in[8];
    const float* fnw = (const float*)d_in[9];
    const float* pk  = (const float*)d_in[10];
    const float* pv  = (const float*)d_in[11];
    float* out = (float*)d_out;

    char* ws = (char*)d_ws;
    constexpr size_t MB = 1ull << 20;
    __bf16* h_bf  = (__bf16*)(ws);              // 8 MB
    float*  xq    = (float*)(ws + 8 * MB);      // 16 MB
    __bf16* xq_bf = (__bf16*)(ws + 24 * MB);    // 8 MB (roped)
    __bf16* ao_bf = (__bf16*)(ws + 32 * MB);    // 8 MB
    float*  xo    = (float*)(ws + 40 * MB);     // 16 MB
    __bf16* hf_bf = (__bf16*)(ws + 56 * MB);    // 8 MB
    float*  x1    = (float*)(ws + 64 * MB);     // 43 MB
    float*  x3    = (float*)(ws + 108 * MB);    // 43 MB
    __bf16* g_bf  = (__bf16*)(ws + 152 * MB);   // 21.5 MB -> total ~174 MB

    rmsnorm_bf16<<<SEQLEN, 256, 0, stream>>>(x, anw, h_bf);
    gemm_bt<<<dim3(HIDDEN / 128, SEQLEN / 128), 256, 0, stream>>>(h_bf, wq, xq, SEQLEN, HIDDEN, HIDDEN);
    rope_cast<<<SEQLEN, 256, 0, stream>>>(xq, xq_bf);
    attn_flash<<<dim3(SEQLEN / 64, NHEADS), 256, 0, stream>>>(xq_bf, pk, pv, ao_bf);
    gemm_bt<<<dim3(HIDDEN / 128, SEQLEN / 128), 256, 0, stream>>>(ao_bf, wo, xo, SEQLEN, HIDDEN, HIDDEN);
    rmsnorm_bf16<<<SEQLEN, 256, 0, stream>>>(xo, fnw, hf_bf);
    gemm_bt<<<dim3(FFN / 128, SEQLEN / 128), 256, 0, stream>>>(hf_bf, w1, x1, SEQLEN, FFN, HIDDEN);
    gemm_bt<<<dim3(FFN / 128, SEQLEN / 128), 256, 0, stream>>>(hf_bf, w3, x3, SEQLEN, FFN, HIDDEN);
    silu_mul_bf16<<<(SEQLEN * FFN) / 1024, 256, 0, stream>>>(x1, x3, g_bf);
    gemm_bt<<<dim3(HIDDEN / 128, SEQLEN / 128), 256, 0, stream>>>(g_bf, w2, out, SEQLEN, HIDDEN, FFN);
}